// Round 2
// baseline (1514.880 us; speedup 1.0000x reference)
//
#include <hip/hip_runtime.h>
#include <hip/hip_bf16.h>

#define B_SZ 4096
#define FEAT 40960
#define HID  1024
#define L1N  64
#define L2N  32
#define IDX_CAP 128
#define ROWS 4

static __device__ __forceinline__ unsigned short f2bf(float x) {
    __hip_bfloat16 h = __float2bfloat16(x);
    return *reinterpret_cast<unsigned short*>(&h);
}
static __device__ __forceinline__ float bf2f(unsigned short u) {
    unsigned int v = ((unsigned int)u) << 16;
    return __uint_as_float(v);
}
static __device__ __forceinline__ float clipf(float x) {
    return fminf(fmaxf(x, 0.0f), 1.0f);
}

// ---------------------------------------------------------------------------
// Kernel 0: transpose ft_w [HID, FEAT] fp32 -> ft_wT [FEAT, HID] bf16
// Tile: 32 features x 64 hid. Stores packed as uint (2 bf16) -> 128 B
// segments per f-row (vs 64 B in round 1).
// ---------------------------------------------------------------------------
__global__ __launch_bounds__(256) void transpose_ftw(
    const float* __restrict__ ftw, unsigned short* __restrict__ ftwT) {
    __shared__ float tile[32][65];   // [f][h], pad -> (tx + h) % 32 banks, conflict-free
    const int tx = threadIdx.x;      // 0..31
    const int ty = threadIdx.y;      // 0..7
    const int f0 = blockIdx.x * 32;
    const int h0 = blockIdx.y * 64;
#pragma unroll
    for (int i = 0; i < 8; ++i) {
        int h = ty + 8 * i;          // 0..63
        tile[tx][h] = ftw[(size_t)(h0 + h) * FEAT + f0 + tx];
    }
    __syncthreads();
#pragma unroll
    for (int i = 0; i < 4; ++i) {
        int f = ty + 8 * i;          // covers 0..31
        float a = tile[f][2 * tx];
        float b = tile[f][2 * tx + 1];
        unsigned int pk = (unsigned int)f2bf(a) | ((unsigned int)f2bf(b) << 16);
        ((unsigned int*)(ftwT + (size_t)(f0 + f) * HID + h0))[tx] = pk;
    }
}

// ---------------------------------------------------------------------------
// Kernel 1 (fused): per block = 4 batch rows.
//  phase A: scan sparse features -> per-(row,persp) index lists in LDS
//  phase B: gather ft_wT columns, accumulate 8 h-slices in registers
//  phase C: stm-select + clip -> h1 in LDS (fp32)
//  phase D: MLP l1(64)+clip -> l2(32)+clip -> l3(1) -> sigmoid, write out
// ---------------------------------------------------------------------------
__global__ __launch_bounds__(256) void nnue_fused(
    const float* __restrict__ wf, const float* __restrict__ bfeat,
    const float* __restrict__ stm, const unsigned short* __restrict__ ftwT,
    const float* __restrict__ ftb,
    const float* __restrict__ l1w, const float* __restrict__ l1b,
    const float* __restrict__ l2w, const float* __restrict__ l2b,
    const float* __restrict__ l3w, const float* __restrict__ l3b,
    float* __restrict__ out) {

    __shared__ int  idx[2][ROWS][IDX_CAP];   // [persp][row][slot]
    __shared__ int  cnt[2][ROWS];
    __shared__ float h1s[ROWS][2 * HID];     // 32 KB
    __shared__ float4 part[4 * L1N];         // l1 partials: [p][k] -> rows in xyzw
    __shared__ float h2s[ROWS][L1N];
    __shared__ float h3s[ROWS][L2N];

    const int t = threadIdx.x;
    const int r0 = blockIdx.x * ROWS;

    if (t < 2 * ROWS) ((int*)cnt)[t] = 0;
    __syncthreads();

    // --- phase A: scan 4 rows x 2 perspectives, float4
    for (int r = 0; r < ROWS; ++r) {
        const float4* wf4 = (const float4*)(wf + (size_t)(r0 + r) * FEAT);
        const float4* bf4 = (const float4*)(bfeat + (size_t)(r0 + r) * FEAT);
        for (int it = 0; it < (FEAT / 4) / 256; ++it) {
            int i4 = it * 256 + t;
            float4 wv = wf4[i4];
            float4 bv = bf4[i4];
            int base = i4 * 4;
            if (wv.x != 0.f) { int p = atomicAdd(&cnt[0][r], 1); if (p < IDX_CAP) idx[0][r][p] = base + 0; }
            if (wv.y != 0.f) { int p = atomicAdd(&cnt[0][r], 1); if (p < IDX_CAP) idx[0][r][p] = base + 1; }
            if (wv.z != 0.f) { int p = atomicAdd(&cnt[0][r], 1); if (p < IDX_CAP) idx[0][r][p] = base + 2; }
            if (wv.w != 0.f) { int p = atomicAdd(&cnt[0][r], 1); if (p < IDX_CAP) idx[0][r][p] = base + 3; }
            if (bv.x != 0.f) { int p = atomicAdd(&cnt[1][r], 1); if (p < IDX_CAP) idx[1][r][p] = base + 0; }
            if (bv.y != 0.f) { int p = atomicAdd(&cnt[1][r], 1); if (p < IDX_CAP) idx[1][r][p] = base + 1; }
            if (bv.z != 0.f) { int p = atomicAdd(&cnt[1][r], 1); if (p < IDX_CAP) idx[1][r][p] = base + 2; }
            if (bv.w != 0.f) { int p = atomicAdd(&cnt[1][r], 1); if (p < IDX_CAP) idx[1][r][p] = base + 3; }
        }
    }
    __syncthreads();

    // --- phase B: gather. thread t owns h = 4t..4t+3 (ushort4 slices).
    float4 bias = ((const float4*)ftb)[t];
    float aw[ROWS][4], ab[ROWS][4];
#pragma unroll
    for (int r = 0; r < ROWS; ++r) {
        aw[r][0] = bias.x; aw[r][1] = bias.y; aw[r][2] = bias.z; aw[r][3] = bias.w;
        ab[r][0] = bias.x; ab[r][1] = bias.y; ab[r][2] = bias.z; ab[r][3] = bias.w;
    }
#pragma unroll
    for (int pp = 0; pp < 2; ++pp) {
        for (int r = 0; r < ROWS; ++r) {
            const int n = min(cnt[pp][r], IDX_CAP);
            float* acc = pp ? ab[r] : aw[r];
#pragma unroll 4
            for (int i = 0; i < n; ++i) {
                int f = idx[pp][r][i];
                ushort4 u = ((const ushort4*)(ftwT + (size_t)f * HID))[t];
                acc[0] += bf2f(u.x); acc[1] += bf2f(u.y);
                acc[2] += bf2f(u.z); acc[3] += bf2f(u.w);
            }
        }
    }

    // --- phase C: stm select + clip -> LDS fp32
#pragma unroll
    for (int r = 0; r < ROWS; ++r) {
        const bool wfirst = (stm[r0 + r] != 0.0f);
#pragma unroll
        for (int c = 0; c < 4; ++c) {
            float fst = wfirst ? aw[r][c] : ab[r][c];
            float snd = wfirst ? ab[r][c] : aw[r][c];
            h1s[r][4 * t + c]       = clipf(fst);
            h1s[r][HID + 4 * t + c] = clipf(snd);
        }
    }
    __syncthreads();

    // --- phase D1: l1. k = t&63 (output), p = t>>6 (wave-uniform K-slice)
    {
        const int k = t & 63, p = t >> 6;
        float a0 = 0.f, a1 = 0.f, a2 = 0.f, a3 = 0.f;
        const float4* w4 = (const float4*)(l1w + (size_t)k * 2 * HID + (size_t)p * 512);
        const int jbase = p * 512;
        for (int jj = 0; jj < 128; ++jj) {
            float4 w = w4[jj];
            int j = jbase + jj * 4;
            a0 += w.x * h1s[0][j] + w.y * h1s[0][j + 1] + w.z * h1s[0][j + 2] + w.w * h1s[0][j + 3];
            a1 += w.x * h1s[1][j] + w.y * h1s[1][j + 1] + w.z * h1s[1][j + 2] + w.w * h1s[1][j + 3];
            a2 += w.x * h1s[2][j] + w.y * h1s[2][j + 1] + w.z * h1s[2][j + 2] + w.w * h1s[2][j + 3];
            a3 += w.x * h1s[3][j] + w.y * h1s[3][j + 1] + w.z * h1s[3][j + 2] + w.w * h1s[3][j + 3];
        }
        part[p * L1N + k] = make_float4(a0, a1, a2, a3);
    }
    __syncthreads();
    if (t < L1N) {
        float4 s0 = part[t], s1 = part[L1N + t], s2 = part[2 * L1N + t], s3 = part[3 * L1N + t];
        float b1 = l1b[t];
        h2s[0][t] = clipf(s0.x + s1.x + s2.x + s3.x + b1);
        h2s[1][t] = clipf(s0.y + s1.y + s2.y + s3.y + b1);
        h2s[2][t] = clipf(s0.z + s1.z + s2.z + s3.z + b1);
        h2s[3][t] = clipf(s0.w + s1.w + s2.w + s3.w + b1);
    }
    __syncthreads();

    // --- phase D2: l2 (128 threads: r = t>>5, k = t&31)
    if (t < ROWS * L2N) {
        int r = t >> 5, k2 = t & 31;
        float a = l2b[k2];
        for (int j = 0; j < L1N; ++j) a += h2s[r][j] * l2w[k2 * L1N + j];
        h3s[r][k2] = clipf(a);
    }
    __syncthreads();

    // --- phase D3: l3 + sigmoid
    if (t < ROWS) {
        float raw = l3b[0];
        for (int j = 0; j < L2N; ++j) raw += h3s[t][j] * l3w[j];
        out[r0 + t] = 1.0f / (1.0f + expf(-raw));
        out[B_SZ + r0 + t] = raw;
    }
}

// ---------------------------------------------------------------------------
extern "C" void kernel_launch(void* const* d_in, const int* in_sizes, int n_in,
                              void* d_out, int out_size, void* d_ws, size_t ws_size,
                              hipStream_t stream) {
    const float* wf    = (const float*)d_in[0];
    const float* bfeat = (const float*)d_in[1];
    const float* stm   = (const float*)d_in[2];
    const float* ftw   = (const float*)d_in[3];
    const float* ftb   = (const float*)d_in[4];
    const float* l1w   = (const float*)d_in[5];
    const float* l1b   = (const float*)d_in[6];
    const float* l2w   = (const float*)d_in[7];
    const float* l2b   = (const float*)d_in[8];
    const float* l3w   = (const float*)d_in[9];
    const float* l3b   = (const float*)d_in[10];
    float* out = (float*)d_out;

    // workspace: ft_wT bf16 [FEAT*HID] = 80 MB
    unsigned short* ftwT = (unsigned short*)d_ws;

    transpose_ftw<<<dim3(FEAT / 32, HID / 64), dim3(32, 8), 0, stream>>>(ftw, ftwT);
    nnue_fused<<<B_SZ / ROWS, 256, 0, stream>>>(wf, bfeat, stm, ftwT, ftb,
                                                l1w, l1b, l2w, l2b, l3w, l3b, out);
}

// Round 3
// 1458.787 us; speedup vs baseline: 1.0385x; 1.0385x over previous
//
#include <hip/hip_runtime.h>
#include <hip/hip_bf16.h>

#define B_SZ 4096
#define FEAT 40960
#define HID  1024
#define L1N  64
#define L2N  32
#define IDX_CAP 128
#define ROWS 4

static __device__ __forceinline__ unsigned short f2bf(float x) {
    __hip_bfloat16 h = __float2bfloat16(x);
    return *reinterpret_cast<unsigned short*>(&h);
}
static __device__ __forceinline__ float bf2f(unsigned short u) {
    unsigned int v = ((unsigned int)u) << 16;
    return __uint_as_float(v);
}
static __device__ __forceinline__ float bf2f_lo(unsigned int u) {
    return __uint_as_float(u << 16);
}
static __device__ __forceinline__ float bf2f_hi(unsigned int u) {
    return __uint_as_float(u & 0xffff0000u);
}
static __device__ __forceinline__ unsigned int packbf(float lo, float hi) {
    return (unsigned int)f2bf(lo) | ((unsigned int)f2bf(hi) << 16);
}
static __device__ __forceinline__ float clipf(float x) {
    return fminf(fmaxf(x, 0.0f), 1.0f);
}

// ---------------------------------------------------------------------------
// Kernel 0: transpose ft_w [HID, FEAT] fp32 -> ft_wT [FEAT, HID] bf16
// ---------------------------------------------------------------------------
__global__ __launch_bounds__(256) void transpose_ftw(
    const float* __restrict__ ftw, unsigned short* __restrict__ ftwT) {
    __shared__ float tile[32][65];
    const int tx = threadIdx.x;      // 0..31
    const int ty = threadIdx.y;      // 0..7
    const int f0 = blockIdx.x * 32;
    const int h0 = blockIdx.y * 64;
#pragma unroll
    for (int i = 0; i < 8; ++i) {
        int h = ty + 8 * i;          // 0..63
        tile[tx][h] = ftw[(size_t)(h0 + h) * FEAT + f0 + tx];
    }
    __syncthreads();
#pragma unroll
    for (int i = 0; i < 4; ++i) {
        int f = ty + 8 * i;          // 0..31
        unsigned int pk = packbf(tile[f][2 * tx], tile[f][2 * tx + 1]);
        ((unsigned int*)(ftwT + (size_t)(f0 + f) * HID + h0))[tx] = pk;
    }
}

// ---------------------------------------------------------------------------
// Kernel 1: scan. One block per (perspective, row). Pure streaming read at
// max occupancy (LDS = 8 bytes, low VGPR). Writes compact index list to ws.
// ---------------------------------------------------------------------------
__global__ __launch_bounds__(256) void scan_kernel(
    const float* __restrict__ wf, const float* __restrict__ bfeat,
    int* __restrict__ idx_ws, int* __restrict__ cnt_ws) {
    __shared__ int cnt;
    const int t = threadIdx.x;
    const int b = blockIdx.x;            // 0 .. 2*B_SZ-1
    const int persp = b >> 12;           // b / B_SZ
    const int row   = b & (B_SZ - 1);
    const float4* s4 = (const float4*)((persp ? bfeat : wf) + (size_t)row * FEAT);
    int* dst = idx_ws + (size_t)b * IDX_CAP;

    if (t == 0) cnt = 0;
    __syncthreads();

#pragma unroll 4
    for (int it = 0; it < (FEAT / 4) / 256; ++it) {
        int i4 = it * 256 + t;
        float4 v = s4[i4];
        int base = i4 * 4;
        if (v.x != 0.f) { int p = atomicAdd(&cnt, 1); if (p < IDX_CAP) dst[p] = base + 0; }
        if (v.y != 0.f) { int p = atomicAdd(&cnt, 1); if (p < IDX_CAP) dst[p] = base + 1; }
        if (v.z != 0.f) { int p = atomicAdd(&cnt, 1); if (p < IDX_CAP) dst[p] = base + 2; }
        if (v.w != 0.f) { int p = atomicAdd(&cnt, 1); if (p < IDX_CAP) dst[p] = base + 3; }
    }
    __syncthreads();
    if (t == 0) cnt_ws[b] = min(cnt, IDX_CAP);
}

// ---------------------------------------------------------------------------
// Kernel 2: gather + MLP. 4 rows per block. h1 held in LDS as packed bf16
// (16 KB) -> ~26 KB total LDS -> 6 blocks/CU.
// ---------------------------------------------------------------------------
__global__ __launch_bounds__(256) void gather_mlp(
    const float* __restrict__ stm, const unsigned short* __restrict__ ftwT,
    const float* __restrict__ ftb,
    const int* __restrict__ idx_ws, const int* __restrict__ cnt_ws,
    const float* __restrict__ l1w, const float* __restrict__ l1b,
    const float* __restrict__ l2w, const float* __restrict__ l2b,
    const float* __restrict__ l3w, const float* __restrict__ l3b,
    float* __restrict__ out) {

    __shared__ int idxs[2 * ROWS][IDX_CAP];      // 4 KB   list l = pp*ROWS + r
    __shared__ int cnts[2 * ROWS];
    __shared__ unsigned int h1p[ROWS][HID];      // 16 KB  (2048 bf16 per row, packed)
    __shared__ float4 part[4 * L1N];             // 4 KB
    __shared__ float h2s[ROWS][L1N];
    __shared__ float h3s[ROWS][L2N];

    const int t = threadIdx.x;
    const int r0 = blockIdx.x * ROWS;

    // --- load counts + index lists into LDS
    if (t < 2 * ROWS) {
        int pp = t >> 2, r = t & 3;
        cnts[t] = cnt_ws[pp * B_SZ + r0 + r];
    }
    for (int i = t; i < 2 * ROWS * IDX_CAP; i += 256) {
        int l = i >> 7;                          // IDX_CAP = 128
        int pp = l >> 2, r = l & 3;
        idxs[l][i & (IDX_CAP - 1)] =
            idx_ws[(size_t)(pp * B_SZ + r0 + r) * IDX_CAP + (i & (IDX_CAP - 1))];
    }
    __syncthreads();

    // --- gather: thread t owns h = 4t..4t+3
    float4 bias = ((const float4*)ftb)[t];
    float acc[2][ROWS][4];
#pragma unroll
    for (int pp = 0; pp < 2; ++pp)
#pragma unroll
        for (int r = 0; r < ROWS; ++r) {
            acc[pp][r][0] = bias.x; acc[pp][r][1] = bias.y;
            acc[pp][r][2] = bias.z; acc[pp][r][3] = bias.w;
        }

#pragma unroll
    for (int pp = 0; pp < 2; ++pp)
#pragma unroll
        for (int r = 0; r < ROWS; ++r) {
            const int n = cnts[pp * ROWS + r];
            float* a = acc[pp][r];
#pragma unroll 4
            for (int i = 0; i < n; ++i) {
                int f = idxs[pp * ROWS + r][i];
                ushort4 u = ((const ushort4*)(ftwT + (size_t)f * HID))[t];
                a[0] += bf2f(u.x); a[1] += bf2f(u.y);
                a[2] += bf2f(u.z); a[3] += bf2f(u.w);
            }
        }

    // --- stm select + clip -> packed bf16 LDS
#pragma unroll
    for (int r = 0; r < ROWS; ++r) {
        const bool wfirst = (stm[r0 + r] != 0.0f);
        const float* fw = acc[0][r];
        const float* fb = acc[1][r];
        float f0 = wfirst ? fw[0] : fb[0], f1 = wfirst ? fw[1] : fb[1];
        float f2 = wfirst ? fw[2] : fb[2], f3 = wfirst ? fw[3] : fb[3];
        float s0 = wfirst ? fb[0] : fw[0], s1 = wfirst ? fb[1] : fw[1];
        float s2 = wfirst ? fb[2] : fw[2], s3 = wfirst ? fb[3] : fw[3];
        h1p[r][2 * t]           = packbf(clipf(f0), clipf(f1));
        h1p[r][2 * t + 1]       = packbf(clipf(f2), clipf(f3));
        h1p[r][512 + 2 * t]     = packbf(clipf(s0), clipf(s1));
        h1p[r][512 + 2 * t + 1] = packbf(clipf(s2), clipf(s3));
    }
    __syncthreads();

    // --- l1: k = t&63 (output neuron), p = t>>6 (wave-uniform K-slice)
    {
        const int k = t & 63, p = t >> 6;
        float a0 = 0.f, a1 = 0.f, a2 = 0.f, a3 = 0.f;
        const float4* w4 = (const float4*)(l1w + (size_t)k * 2 * HID + (size_t)p * 512);
        const int qbase = p * 256;
        for (int jj = 0; jj < 128; ++jj) {
            float4 w = w4[jj];
            int q = qbase + 2 * jj;
            unsigned int u00 = h1p[0][q], u01 = h1p[0][q + 1];
            unsigned int u10 = h1p[1][q], u11 = h1p[1][q + 1];
            unsigned int u20 = h1p[2][q], u21 = h1p[2][q + 1];
            unsigned int u30 = h1p[3][q], u31 = h1p[3][q + 1];
            a0 += w.x * bf2f_lo(u00) + w.y * bf2f_hi(u00) + w.z * bf2f_lo(u01) + w.w * bf2f_hi(u01);
            a1 += w.x * bf2f_lo(u10) + w.y * bf2f_hi(u10) + w.z * bf2f_lo(u11) + w.w * bf2f_hi(u11);
            a2 += w.x * bf2f_lo(u20) + w.y * bf2f_hi(u20) + w.z * bf2f_lo(u21) + w.w * bf2f_hi(u21);
            a3 += w.x * bf2f_lo(u30) + w.y * bf2f_hi(u30) + w.z * bf2f_lo(u31) + w.w * bf2f_hi(u31);
        }
        part[p * L1N + k] = make_float4(a0, a1, a2, a3);
    }
    __syncthreads();
    if (t < L1N) {
        float4 s0 = part[t], s1 = part[L1N + t], s2 = part[2 * L1N + t], s3 = part[3 * L1N + t];
        float b1 = l1b[t];
        h2s[0][t] = clipf(s0.x + s1.x + s2.x + s3.x + b1);
        h2s[1][t] = clipf(s0.y + s1.y + s2.y + s3.y + b1);
        h2s[2][t] = clipf(s0.z + s1.z + s2.z + s3.z + b1);
        h2s[3][t] = clipf(s0.w + s1.w + s2.w + s3.w + b1);
    }
    __syncthreads();

    // --- l2 (128 threads: r = t>>5, k = t&31)
    if (t < ROWS * L2N) {
        int r = t >> 5, k2 = t & 31;
        float a = l2b[k2];
        for (int j = 0; j < L1N; ++j) a += h2s[r][j] * l2w[k2 * L1N + j];
        h3s[r][k2] = clipf(a);
    }
    __syncthreads();

    // --- l3 + sigmoid
    if (t < ROWS) {
        float raw = l3b[0];
        for (int j = 0; j < L2N; ++j) raw += h3s[t][j] * l3w[j];
        out[r0 + t] = 1.0f / (1.0f + expf(-raw));
        out[B_SZ + r0 + t] = raw;
    }
}

// ---------------------------------------------------------------------------
extern "C" void kernel_launch(void* const* d_in, const int* in_sizes, int n_in,
                              void* d_out, int out_size, void* d_ws, size_t ws_size,
                              hipStream_t stream) {
    const float* wf    = (const float*)d_in[0];
    const float* bfeat = (const float*)d_in[1];
    const float* stm   = (const float*)d_in[2];
    const float* ftw   = (const float*)d_in[3];
    const float* ftb   = (const float*)d_in[4];
    const float* l1w   = (const float*)d_in[5];
    const float* l1b   = (const float*)d_in[6];
    const float* l2w   = (const float*)d_in[7];
    const float* l2b   = (const float*)d_in[8];
    const float* l3w   = (const float*)d_in[9];
    const float* l3b   = (const float*)d_in[10];
    float* out = (float*)d_out;

    // ws layout: ftwT bf16 [FEAT*HID] (80 MB) | idx [2*B*IDX_CAP] (4 MB) | cnt [2*B]
    unsigned short* ftwT = (unsigned short*)d_ws;
    int* idx_ws = (int*)(ftwT + (size_t)FEAT * HID);
    int* cnt_ws = idx_ws + (size_t)2 * B_SZ * IDX_CAP;

    transpose_ftw<<<dim3(FEAT / 32, HID / 64), dim3(32, 8), 0, stream>>>(ftw, ftwT);
    scan_kernel<<<2 * B_SZ, 256, 0, stream>>>(wf, bfeat, idx_ws, cnt_ws);
    gather_mlp<<<B_SZ / ROWS, 256, 0, stream>>>(stm, ftwT, ftb, idx_ws, cnt_ws,
                                                l1w, l1b, l2w, l2b, l3w, l3b, out);
}

// Round 4
// 1451.104 us; speedup vs baseline: 1.0440x; 1.0053x over previous
//
#include <hip/hip_runtime.h>
#include <hip/hip_bf16.h>

#define B_SZ 4096
#define FEAT 40960
#define HID  1024
#define L1N  64
#define L2N  32
#define IDX_CAP 128
#define ROWS 4

static __device__ __forceinline__ unsigned short f2bf(float x) {
    __hip_bfloat16 h = __float2bfloat16(x);
    return *reinterpret_cast<unsigned short*>(&h);
}
static __device__ __forceinline__ float bf2f(unsigned short u) {
    return __uint_as_float(((unsigned int)u) << 16);
}
static __device__ __forceinline__ float bf2f_lo(unsigned int u) {
    return __uint_as_float(u << 16);
}
static __device__ __forceinline__ float bf2f_hi(unsigned int u) {
    return __uint_as_float(u & 0xffff0000u);
}
static __device__ __forceinline__ unsigned int packbf(float lo, float hi) {
    return (unsigned int)f2bf(lo) | ((unsigned int)f2bf(hi) << 16);
}
static __device__ __forceinline__ float clipf(float x) {
    return fminf(fmaxf(x, 0.0f), 1.0f);
}

// ---------------------------------------------------------------------------
// Kernel 0: transpose ft_w [HID, FEAT] fp32 -> ft_wT [FEAT, HID] bf16
// ---------------------------------------------------------------------------
__global__ __launch_bounds__(256) void transpose_ftw(
    const float* __restrict__ ftw, unsigned short* __restrict__ ftwT) {
    __shared__ float tile[32][65];
    const int tx = threadIdx.x;      // 0..31
    const int ty = threadIdx.y;      // 0..7
    const int f0 = blockIdx.x * 32;
    const int h0 = blockIdx.y * 64;
#pragma unroll
    for (int i = 0; i < 8; ++i) {
        int h = ty + 8 * i;          // 0..63
        tile[tx][h] = ftw[(size_t)(h0 + h) * FEAT + f0 + tx];
    }
    __syncthreads();
#pragma unroll
    for (int i = 0; i < 4; ++i) {
        int f = ty + 8 * i;          // 0..31
        unsigned int pk = packbf(tile[f][2 * tx], tile[f][2 * tx + 1]);
        ((unsigned int*)(ftwT + (size_t)(f0 + f) * HID + h0))[tx] = pk;
    }
}

// ---------------------------------------------------------------------------
// Kernel 1: fused scan + gather. One block per batch row, both perspectives.
// LDS footprint ~1.3 KB -> occupancy limited only by VGPRs (~8 waves/SIMD).
// The gather's L3-resident ft_wT traffic hides under the HBM feature stream
// of other resident blocks. Writes h1 packed bf16 [B][1024] uints to ws.
// ---------------------------------------------------------------------------
__global__ __launch_bounds__(256) void scan_gather(
    const float* __restrict__ wf, const float* __restrict__ bfeat,
    const float* __restrict__ stm, const unsigned short* __restrict__ ftwT,
    const float* __restrict__ ftb, unsigned int* __restrict__ h1) {

    __shared__ int idxs[2][IDX_CAP];
    __shared__ int cnts[2];

    const int t = threadIdx.x;
    const int row = blockIdx.x;

    if (t < 2) cnts[t] = 0;
    __syncthreads();

    // --- scan both perspectives (2 x 160 KB streaming, float4)
#pragma unroll
    for (int pp = 0; pp < 2; ++pp) {
        const float4* s4 = (const float4*)((pp ? bfeat : wf) + (size_t)row * FEAT);
#pragma unroll 4
        for (int it = 0; it < (FEAT / 4) / 256; ++it) {
            int i4 = it * 256 + t;
            float4 v = s4[i4];
            int base = i4 * 4;
            if (v.x != 0.f) { int p = atomicAdd(&cnts[pp], 1); if (p < IDX_CAP) idxs[pp][p] = base + 0; }
            if (v.y != 0.f) { int p = atomicAdd(&cnts[pp], 1); if (p < IDX_CAP) idxs[pp][p] = base + 1; }
            if (v.z != 0.f) { int p = atomicAdd(&cnts[pp], 1); if (p < IDX_CAP) idxs[pp][p] = base + 2; }
            if (v.w != 0.f) { int p = atomicAdd(&cnts[pp], 1); if (p < IDX_CAP) idxs[pp][p] = base + 3; }
        }
    }
    __syncthreads();

    // --- gather: thread t owns h = 4t..4t+3
    const int nw = min(cnts[0], IDX_CAP);
    const int nb = min(cnts[1], IDX_CAP);
    float4 bias = ((const float4*)ftb)[t];
    float aw0 = bias.x, aw1 = bias.y, aw2 = bias.z, aw3 = bias.w;
    float ab0 = bias.x, ab1 = bias.y, ab2 = bias.z, ab3 = bias.w;

#pragma unroll 4
    for (int i = 0; i < nw; ++i) {
        int f = idxs[0][i];
        ushort4 u = ((const ushort4*)(ftwT + (size_t)f * HID))[t];
        aw0 += bf2f(u.x); aw1 += bf2f(u.y); aw2 += bf2f(u.z); aw3 += bf2f(u.w);
    }
#pragma unroll 4
    for (int i = 0; i < nb; ++i) {
        int f = idxs[1][i];
        ushort4 u = ((const ushort4*)(ftwT + (size_t)f * HID))[t];
        ab0 += bf2f(u.x); ab1 += bf2f(u.y); ab2 += bf2f(u.z); ab3 += bf2f(u.w);
    }

    // --- stm select + clip + pack -> global h1 (two uint2 stores)
    const bool wfirst = (stm[row] != 0.0f);
    float f0 = wfirst ? aw0 : ab0, f1 = wfirst ? aw1 : ab1;
    float f2 = wfirst ? aw2 : ab2, f3 = wfirst ? aw3 : ab3;
    float s0 = wfirst ? ab0 : aw0, s1 = wfirst ? ab1 : aw1;
    float s2 = wfirst ? ab2 : aw2, s3 = wfirst ? ab3 : aw3;

    uint2 pf, ps;
    pf.x = packbf(clipf(f0), clipf(f1)); pf.y = packbf(clipf(f2), clipf(f3));
    ps.x = packbf(clipf(s0), clipf(s1)); ps.y = packbf(clipf(s2), clipf(s3));

    unsigned int* dst = h1 + (size_t)row * (2 * HID / 2);
    ((uint2*)dst)[t]                 = pf;   // first-perspective half: uints 2t,2t+1
    ((uint2*)(dst + HID / 2 * 1))[t + 0] = ps;   // second half at offset 512 uints
}

// ---------------------------------------------------------------------------
// Kernel 2: MLP. 4 rows/block; h1 packed bf16 staged to LDS (16 KB).
// ---------------------------------------------------------------------------
__global__ __launch_bounds__(256) void mlp_kernel(
    const unsigned int* __restrict__ h1,
    const float* __restrict__ l1w, const float* __restrict__ l1b,
    const float* __restrict__ l2w, const float* __restrict__ l2b,
    const float* __restrict__ l3w, const float* __restrict__ l3b,
    float* __restrict__ out) {

    __shared__ unsigned int h1p[ROWS][HID];      // 16 KB packed bf16
    __shared__ float4 part[4 * L1N];             // 4 KB
    __shared__ float h2s[ROWS][L1N];
    __shared__ float h3s[ROWS][L2N];

    const int t = threadIdx.x;
    const int r0 = blockIdx.x * ROWS;

    // stage h1: 4 rows x 1024 uints = 4096 uints; uint4 x 4 per thread
    {
        const uint4* src = (const uint4*)(h1 + (size_t)r0 * HID);
        uint4* dst = (uint4*)&h1p[0][0];
#pragma unroll
        for (int i = 0; i < 4; ++i) dst[i * 256 + t] = src[i * 256 + t];
    }
    __syncthreads();

    // --- l1: k = t&63 (output neuron), p = t>>6 (wave-uniform K-slice)
    {
        const int k = t & 63, p = t >> 6;
        float a0 = 0.f, a1 = 0.f, a2 = 0.f, a3 = 0.f;
        const float4* w4 = (const float4*)(l1w + (size_t)k * 2 * HID + (size_t)p * 512);
        const int qbase = p * 256;
        for (int jj = 0; jj < 128; ++jj) {
            float4 w = w4[jj];
            int q = qbase + 2 * jj;
            unsigned int u00 = h1p[0][q], u01 = h1p[0][q + 1];
            unsigned int u10 = h1p[1][q], u11 = h1p[1][q + 1];
            unsigned int u20 = h1p[2][q], u21 = h1p[2][q + 1];
            unsigned int u30 = h1p[3][q], u31 = h1p[3][q + 1];
            a0 += w.x * bf2f_lo(u00) + w.y * bf2f_hi(u00) + w.z * bf2f_lo(u01) + w.w * bf2f_hi(u01);
            a1 += w.x * bf2f_lo(u10) + w.y * bf2f_hi(u10) + w.z * bf2f_lo(u11) + w.w * bf2f_hi(u11);
            a2 += w.x * bf2f_lo(u20) + w.y * bf2f_hi(u20) + w.z * bf2f_lo(u21) + w.w * bf2f_hi(u21);
            a3 += w.x * bf2f_lo(u30) + w.y * bf2f_hi(u30) + w.z * bf2f_lo(u31) + w.w * bf2f_hi(u31);
        }
        part[p * L1N + k] = make_float4(a0, a1, a2, a3);
    }
    __syncthreads();
    if (t < L1N) {
        float4 s0 = part[t], s1 = part[L1N + t], s2 = part[2 * L1N + t], s3 = part[3 * L1N + t];
        float b1 = l1b[t];
        h2s[0][t] = clipf(s0.x + s1.x + s2.x + s3.x + b1);
        h2s[1][t] = clipf(s0.y + s1.y + s2.y + s3.y + b1);
        h2s[2][t] = clipf(s0.z + s1.z + s2.z + s3.z + b1);
        h2s[3][t] = clipf(s0.w + s1.w + s2.w + s3.w + b1);
    }
    __syncthreads();

    // --- l2 (128 threads: r = t>>5, k = t&31)
    if (t < ROWS * L2N) {
        int r = t >> 5, k2 = t & 31;
        float a = l2b[k2];
        for (int j = 0; j < L1N; ++j) a += h2s[r][j] * l2w[k2 * L1N + j];
        h3s[r][k2] = clipf(a);
    }
    __syncthreads();

    // --- l3 + sigmoid
    if (t < ROWS) {
        float raw = l3b[0];
        for (int j = 0; j < L2N; ++j) raw += h3s[t][j] * l3w[j];
        out[r0 + t] = 1.0f / (1.0f + expf(-raw));
        out[B_SZ + r0 + t] = raw;
    }
}

// ---------------------------------------------------------------------------
extern "C" void kernel_launch(void* const* d_in, const int* in_sizes, int n_in,
                              void* d_out, int out_size, void* d_ws, size_t ws_size,
                              hipStream_t stream) {
    const float* wf    = (const float*)d_in[0];
    const float* bfeat = (const float*)d_in[1];
    const float* stm   = (const float*)d_in[2];
    const float* ftw   = (const float*)d_in[3];
    const float* ftb   = (const float*)d_in[4];
    const float* l1w   = (const float*)d_in[5];
    const float* l1b   = (const float*)d_in[6];
    const float* l2w   = (const float*)d_in[7];
    const float* l2b   = (const float*)d_in[8];
    const float* l3w   = (const float*)d_in[9];
    const float* l3b   = (const float*)d_in[10];
    float* out = (float*)d_out;

    // ws layout: ftwT bf16 [FEAT*HID] (80 MB) | h1 packed [B_SZ*HID] uints (16 MB)
    unsigned short* ftwT = (unsigned short*)d_ws;
    unsigned int* h1 = (unsigned int*)(ftwT + (size_t)FEAT * HID);

    transpose_ftw<<<dim3(FEAT / 32, HID / 64), dim3(32, 8), 0, stream>>>(ftw, ftwT);
    scan_gather<<<B_SZ, 256, 0, stream>>>(wf, bfeat, stm, ftwT, ftb, h1);
    mlp_kernel<<<B_SZ / ROWS, 256, 0, stream>>>(h1, l1w, l1b, l2w, l2b, l3w, l3b, out);
}